// Round 11
// baseline (1192.698 us; speedup 1.0000x reference)
//
#include <hip/hip_runtime.h>
#include <hip/hip_bf16.h>

#define BATCH   16
#define NPTS    4096
#define CIN     256
#define COUT    512
#define KNN     16
#define NOUT    1024
#define XOUT_ELEMS 8388608   // 16*1024*512
#define LDA     40           // padded LDS leading dim (bf16 elems), known-good
#define GEMM_BLOCKS 2048
#define GATHER_BLOCKS 8192
#define DYN_LDS 53312        // 3*4096*4 (xyz) + 64 (warr) + 4096 (wins)

typedef __attribute__((ext_vector_type(4))) float f32x4;
typedef __attribute__((ext_vector_type(2))) float f32x2;
typedef __attribute__((ext_vector_type(8))) short bf16x8;
typedef unsigned long long u64;

__device__ __forceinline__ unsigned short f2bf_rne(float f) {
    unsigned u = __float_as_uint(f);
    return (unsigned short)((u + 0x7FFFu + ((u >> 16) & 1u)) >> 16);
}
__device__ __forceinline__ float bf2f(unsigned short s) {
    return __uint_as_float(((unsigned)s) << 16);
}

// 6-step DPP max-reduce across 64 lanes; lane 63 ends with the max (HW-validated R1).
__device__ __forceinline__ float wave_max_dpp(float v) {
    int x, y;
    x = __float_as_int(v);
    y = __builtin_amdgcn_update_dpp(x, x, 0x111, 0xf, 0xf, false);
    v = fmaxf(v, __int_as_float(y)); x = __float_as_int(v);
    y = __builtin_amdgcn_update_dpp(x, x, 0x112, 0xf, 0xf, false);
    v = fmaxf(v, __int_as_float(y)); x = __float_as_int(v);
    y = __builtin_amdgcn_update_dpp(x, x, 0x114, 0xf, 0xf, false);
    v = fmaxf(v, __int_as_float(y)); x = __float_as_int(v);
    y = __builtin_amdgcn_update_dpp(x, x, 0x118, 0xf, 0xf, false);
    v = fmaxf(v, __int_as_float(y)); x = __float_as_int(v);
    y = __builtin_amdgcn_update_dpp(x, x, 0x142, 0xf, 0xf, false);
    v = fmaxf(v, __int_as_float(y)); x = __float_as_int(v);
    y = __builtin_amdgcn_update_dpp(x, x, 0x143, 0xf, 0xf, false);
    v = fmaxf(v, __int_as_float(y));
    return v;
}

// One kernel, 256 thr/block:
//   [0,16)        FPS (R9 loop + in-loop fid publish, setprio 3)
//   [16,2064)     GEMM -> h, publishes done-counter (R2-proven idiom)
//   [2064,10256)  gather+maxpool, 2 pts/block (R2-proven spin idiom)
extern "C" __global__ void __launch_bounds__(256)
fused_all(const float* __restrict__ x, const float* __restrict__ p,
          const int* __restrict__ sid32, const float* __restrict__ W,
          const float* __restrict__ bias, const float* __restrict__ gamma,
          const float* __restrict__ beta, const float* __restrict__ rmean,
          const float* __restrict__ rvar, int* __restrict__ fid,
          unsigned* __restrict__ cnt, unsigned short* __restrict__ h,
          float* __restrict__ out)
{
    extern __shared__ char smem[];
    const int t = threadIdx.x;
    const int lane = t & 63;
    const int wv = t >> 6;

    if (blockIdx.x < BATCH) {
        // ---------------- FPS: exact replica of numpy f32 arithmetic ----------------
#pragma clang fp contract(off)
        __builtin_amdgcn_s_setprio(3);     // win issue arbitration vs co-resident waves
        const int b = blockIdx.x;
        float* lx = (float*)smem;                        // [4096]
        float* ly = lx + NPTS;
        float* lz = ly + NPTS;
        u64* warr = (u64*)(smem + 49152);                // [2][4] parity dbuf keys
        int* wins = (int*)(smem + 49216);                // [1024] winner indices
        float* pout = out + XOUT_ELEMS + (size_t)b * NOUT * 3;

        const float* pb = p + (size_t)b * NPTS * 3;
        for (int l = t; l < NPTS * 3; l += 256) {
            float v = pb[l];
            int pi = l / 3;
            int c = l - pi * 3;
            if (c == 0) lx[pi] = v; else if (c == 1) ly[pi] = v; else lz[pi] = v;
        }
        if (t == 0) {
            wins[0] = 0;
            __hip_atomic_store(&fid[b * NOUT], b * NPTS, __ATOMIC_RELAXED,
                               __HIP_MEMORY_SCOPE_AGENT);
        }
        __syncthreads();

        // thread t owns points [16t,16t+16): lowest lane == lowest point index,
        // so ballot+ctz reproduces np.argmax first-occurrence exactly.
        f32x2 px2[8], py2[8], pz2[8], d2[8];
        const int base = t << 4;
#pragma unroll
        for (int j = 0; j < 8; ++j) {
            px2[j] = *(const f32x2*)(lx + base + (j << 1));
            py2[j] = *(const f32x2*)(ly + base + (j << 1));
            pz2[j] = *(const f32x2*)(lz + base + (j << 1));
            d2[j]  = (f32x2){3.4028235e38f, 3.4028235e38f}; // min(FLT_MAX,d0)==d0
        }

        int winner = 0;
        for (int i = 1; i < NOUT; ++i) {
            float wx = lx[winner], wy = ly[winner], wz = lz[winner]; // LDS bcast
            f32x2 wx2 = {wx, wx}, wy2 = {wy, wy}, wz2 = {wz, wz};
            float bestd = -1.0f;
            int   bestj = 0;
#pragma unroll
            for (int j = 0; j < 8; ++j) {
                // np semantics: ((dx*dx + dy*dy) + dz*dz), RN, no fma (contract off)
                f32x2 dx = px2[j] - wx2;
                f32x2 dy = py2[j] - wy2;
                f32x2 dz = pz2[j] - wz2;
                f32x2 s  = ((dx * dx) + (dy * dy)) + (dz * dz);
                f32x2 nd;
                nd.x = fminf(d2[j].x, s.x);
                nd.y = fminf(d2[j].y, s.y);
                d2[j] = nd;
                bool g0 = nd.x > bestd;            // strict >: earliest idx wins
                bestd = g0 ? nd.x : bestd;
                bestj = g0 ? (j << 1) : bestj;
                bool g1 = nd.y > bestd;
                bestd = g1 ? nd.y : bestd;
                bestj = g1 ? (j << 1) + 1 : bestj;
            }
            // wave argmax (value via DPP, first-lane tie-break via ballot)
            float vmax = wave_max_dpp(bestd);
            float wmax = __int_as_float(
                __builtin_amdgcn_readlane(__float_as_int(vmax), 63));
            u64 msk = __ballot(bestd == wmax);
            int lead = (int)__builtin_ctzll(msk);
            int wbpi = __builtin_amdgcn_readlane(base + bestj, lead);
            // d>=0: f32 bits order-isomorphic as unsigned; low word prefers
            // LOWEST point index on cross-wave ties.
            u64 key = ((u64)__float_as_uint(wmax) << 32)
                    | (unsigned)(NPTS - 1 - wbpi);
            u64* wrow = warr + ((i & 1) << 2);     // parity dbuf: 1 barrier/iter
            if (lane == 0) wrow[wv] = key;
            __syncthreads();
            u64 k0 = wrow[0], k1 = wrow[1], k2 = wrow[2], k3 = wrow[3];
            if (k1 > k0) k0 = k1;
            if (k3 > k2) k2 = k3;
            if (k2 > k0) k0 = k2;
            winner = NPTS - 1 - (int)(unsigned)(k0 & 0xffffffffull);
            if (t == 0) {
                wins[i] = winner;                  // LDS (for p_out epilogue)
                __hip_atomic_store(&fid[b * NOUT + i], b * NPTS + winner,
                                   __ATOMIC_RELAXED, __HIP_MEMORY_SCOPE_AGENT);
            }
        }
        // epilogue: p_out bulk write (off the critical path)
        __syncthreads();
        for (int i = t; i < NOUT; i += 256) {
            int w = wins[i];
            float* po = pout + (size_t)i * 3;
            po[0] = lx[w]; po[1] = ly[w]; po[2] = lz[w];
        }
    } else if (blockIdx.x < BATCH + GEMM_BLOCKS) {
        // ---------------- GEMM: h = relu(BN(x @ W^T + b)), bf16 MFMA ----------------
        const int bid = blockIdx.x - BATCH;
        const int bm = bid >> 2;           // 512 M-tiles of 128
        const int bn = bid & 3;            // 4 N-tiles of 128
        short* As = (short*)smem;          // [128][LDA]
        short* Bs = As + 128 * LDA;        // [128][LDA] (W is [n][k] = B^T)

        const int wm = wv >> 1, wn = wv & 1;   // 2x2 waves, 64x64 each
        const int quad = lane >> 4, l16 = lane & 15;
        const int m0 = bm * 128, n0 = bn * 128;

        f32x4 acc[4][4];
        const f32x4 zero = {0.0f, 0.0f, 0.0f, 0.0f};
#pragma unroll
        for (int a = 0; a < 4; ++a)
#pragma unroll
            for (int bb = 0; bb < 4; ++bb) acc[a][bb] = zero;

        const int srow = t >> 3;           // 0..31
        const int scol = (t & 7) << 2;     // 0..28

        for (int ks = 0; ks < 8; ++ks) {   // K=256 in steps of 32
            const int k0 = ks * 32;
            __syncthreads();
#pragma unroll
            for (int it = 0; it < 4; ++it) {
                int row = srow + it * 32;
                float4 va = *(const float4*)(x + (size_t)(m0 + row) * CIN + k0 + scol);
                short4 pa = make_short4((short)f2bf_rne(va.x), (short)f2bf_rne(va.y),
                                        (short)f2bf_rne(va.z), (short)f2bf_rne(va.w));
                *(short4*)(As + row * LDA + scol) = pa;
                float4 vb = *(const float4*)(W + (size_t)(n0 + row) * CIN + k0 + scol);
                short4 pb2 = make_short4((short)f2bf_rne(vb.x), (short)f2bf_rne(vb.y),
                                         (short)f2bf_rne(vb.z), (short)f2bf_rne(vb.w));
                *(short4*)(Bs + row * LDA + scol) = pb2;
            }
            __syncthreads();
            bf16x8 af[4], bfr[4];
#pragma unroll
            for (int tm = 0; tm < 4; ++tm)
                af[tm] = *(const bf16x8*)(As + (wm * 64 + tm * 16 + l16) * LDA + quad * 8);
#pragma unroll
            for (int tn = 0; tn < 4; ++tn)
                bfr[tn] = *(const bf16x8*)(Bs + (wn * 64 + tn * 16 + l16) * LDA + quad * 8);
#pragma unroll
            for (int tm = 0; tm < 4; ++tm)
#pragma unroll
                for (int tn = 0; tn < 4; ++tn)
                    acc[tm][tn] = __builtin_amdgcn_mfma_f32_16x16x32_bf16(
                        af[tm], bfr[tn], acc[tm][tn], 0, 0, 0);
        }
#pragma unroll
        for (int tn = 0; tn < 4; ++tn) {
            int c = n0 + wn * 64 + tn * 16 + l16;
            float sc = gamma[c] / sqrtf(rvar[c] + 1e-5f);
            float sh = (bias[c] - rmean[c]) * sc + beta[c];
#pragma unroll
            for (int tm = 0; tm < 4; ++tm) {
                int rbase = m0 + wm * 64 + tm * 16 + quad * 4;
#pragma unroll
                for (int r = 0; r < 4; ++r) {
                    float v = fmaxf(acc[tm][tn][r] * sc + sh, 0.0f);
                    h[(size_t)(rbase + r) * COUT + c] = f2bf_rne(v);
                }
            }
        }
        // publish (R2-proven): all h stores visible device-wide, then count tile
        __threadfence();
        __syncthreads();
        if (t == 0)
            __hip_atomic_fetch_add(cnt, 1u, __ATOMIC_RELEASE,
                                   __HIP_MEMORY_SCOPE_AGENT);
    } else {
        // ------------ gather+maxpool: 2 output points per block (R2-proven) ---------
        const int gb = blockIdx.x - (BATCH + GEMM_BLOCKS);
        const int j0 = gb << 1;
        int* rows  = (int*)smem;           // [2][16]
        int* frows = rows + 32;            // [2]
        const int g = t >> 7, tl = t & 127;

        if (tl == 0) {
            if (g == 0) {   // wait for all GEMM tiles (h fully written)
                long guard = 0;
                unsigned c;
                do {
                    c = __hip_atomic_load(cnt, __ATOMIC_ACQUIRE,
                                          __HIP_MEMORY_SCOPE_AGENT);
                    if (c >= (unsigned)GEMM_BLOCKS) break;
                    __builtin_amdgcn_s_sleep(32);
                } while (++guard < (1 << 21));
            }
            long guard = 0;
            int v;
            do {            // wait for this point's FPS index
                v = __hip_atomic_load(&fid[j0 + g], __ATOMIC_RELAXED,
                                      __HIP_MEMORY_SCOPE_AGENT);
                if (v >= 0) break;
                __builtin_amdgcn_s_sleep(16);
            } while (++guard < (1 << 21));
            frows[g] = (v >= 0) ? v : 0;
            __threadfence();   // acquire side: drop stale cached h lines
        }
        __syncthreads();
        const int frow = frows[g];
        // sid_euc may be int32 or int64 (JAX x64 ambiguity); sniff high words.
        bool is64 = (sid32[1] == 0) && (sid32[3] == 0) && (sid32[5] == 0);
        if (tl < KNN) {
            long long e = (long long)frow * KNN + tl;
            rows[g * KNN + tl] = is64 ? sid32[e * 2] : sid32[e];
        }
        __syncthreads();

        const int c4 = tl << 2;
        float m0 = -3.4028235e38f, m1 = m0, m2 = m0, m3 = m0;
#pragma unroll
        for (int k = 0; k < KNN; ++k) {
            const ushort4 v = *(const ushort4*)(h + (size_t)rows[g * KNN + k] * COUT + c4);
            m0 = fmaxf(m0, bf2f(v.x));
            m1 = fmaxf(m1, bf2f(v.y));
            m2 = fmaxf(m2, bf2f(v.z));
            m3 = fmaxf(m3, bf2f(v.w));
        }
        *(float4*)(out + (size_t)(j0 + g) * COUT + c4) = make_float4(m0, m1, m2, m3);
    }
}

extern "C" void kernel_launch(void* const* d_in, const int* in_sizes, int n_in,
                              void* d_out, int out_size, void* d_ws, size_t ws_size,
                              hipStream_t stream)
{
    const float* x     = (const float*)d_in[0];
    const float* p     = (const float*)d_in[1];
    const int*   sid   = (const int*)d_in[2];   // tid_euc (d_in[3]) unused
    const float* W     = (const float*)d_in[4];
    const float* bias  = (const float*)d_in[5];
    const float* gamma = (const float*)d_in[6];
    const float* beta  = (const float*)d_in[7];
    const float* rmean = (const float*)d_in[8];
    const float* rvar  = (const float*)d_in[9];
    float* out = (float*)d_out;

    int*      fid = (int*)d_ws;                                  // [16384] @ 0
    unsigned* cnt = (unsigned*)((char*)d_ws + 65536);            // [1]
    unsigned short* h = (unsigned short*)((char*)d_ws + 65792);  // 65536x512 bf16

    (void)hipMemsetAsync(d_ws, 0xFF, 65536, stream);             // fid = -1
    (void)hipMemsetAsync((char*)d_ws + 65536, 0, 4, stream);     // cnt = 0

    hipLaunchKernelGGL(fused_all, dim3(BATCH + GEMM_BLOCKS + GATHER_BLOCKS),
                       dim3(256), DYN_LDS, stream,
                       x, p, sid, W, bias, gamma, beta, rmean, rvar,
                       fid, cnt, h, out);
}